// Round 3
// baseline (1014.139 us; speedup 1.0000x reference)
//
#include <hip/hip_runtime.h>
#include <hip/hip_bf16.h>
#include <math.h>

using bf16 = __hip_bfloat16;
typedef __attribute__((ext_vector_type(4))) float f32x4;
typedef __attribute__((ext_vector_type(8))) short s16x8;

#define BM 128
#define BN 128
#define BK 32

__device__ inline short f2b(float f) {
  bf16 h = __float2bfloat16(f);
  short s; __builtin_memcpy(&s, &h, 2); return s;
}

// load 8 contiguous elements starting at elemOff; convert fp32->bf16 if needed
template<bool F32>
__device__ inline s16x8 load8(const void* base, size_t elemOff) {
  s16x8 r;
  if (F32) {
    const float* p = (const float*)base + elemOff;
    f32x4 a = *(const f32x4*)p;
    f32x4 b = *(const f32x4*)(p + 4);
    r[0] = f2b(a[0]); r[1] = f2b(a[1]); r[2] = f2b(a[2]); r[3] = f2b(a[3]);
    r[4] = f2b(b[0]); r[5] = f2b(b[1]); r[6] = f2b(b[2]); r[7] = f2b(b[3]);
  } else {
    r = *(const s16x8*)((const bf16*)base + elemOff);
  }
  return r;
}

// NT GEMM: C[m][n] = alpha * sum_k A[m][k]*B[n][k]
// MODE 0: projection scatter into (H*B,S,hd): row=s*16+b, col=h*512+e
// MODE 1: scores, z in [0,64): A,B += z*262144; C += (z&15)*1048576+(z>>4)*512, ldc=2048
// MODE 2: PV: A += (z&15)*1048576+(z>>4)*512 (lda 2048); B += z*262144; C += ((z&15)*4+(z>>4))*262144
// MODE 3: plain row-major
template<int MODE, bool AF32, bool BF32, bool CF32>
__global__ __launch_bounds__(256) void gemm_nt(const void* __restrict__ Ain,
    const void* __restrict__ Bin, void* __restrict__ Cout,
    int K, int lda, int ldb, int ldc, float alpha)
{
  __shared__ bf16 sA[BM * BK];
  __shared__ bf16 sB[BN * BK];

  const int tid  = threadIdx.x;
  const int lane = tid & 63;
  const int wave = tid >> 6;
  const int quad = lane >> 4;
  const int l16  = lane & 15;

  size_t aBase = 0, bBase = 0, cBase = 0;
  if (MODE == 1) {
    const int z = blockIdx.z;
    aBase = (size_t)z * 262144;
    bBase = (size_t)z * 262144;
    cBase = (size_t)(z & 15) * 1048576 + (size_t)(z >> 4) * 512;
  } else if (MODE == 2) {
    const int z = blockIdx.z;
    aBase = (size_t)(z & 15) * 1048576 + (size_t)(z >> 4) * 512;
    bBase = (size_t)z * 262144;
    cBase = (size_t)((z & 15) * 4 + (z >> 4)) * 262144;
  }

  const int tileM = blockIdx.y * BM;
  const int tileN = blockIdx.x * BN;

  // staging: thread t handles 8 elems at row (t>>2), col ((t&3)*8); two 64-row halves
  const int sRow = tid >> 2;
  const int sCol = (tid & 3) * 8;
  const size_t aOff = aBase + (size_t)(tileM + sRow) * lda + sCol;
  const size_t bOff = bBase + (size_t)(tileN + sRow) * ldb + sCol;
  const size_t aStep = (size_t)64 * lda;
  const size_t bStep = (size_t)64 * ldb;

  const int warpRow = (wave >> 1) * 64;
  const int warpCol = (wave & 1) * 64;

  f32x4 acc[4][4] = {};

  for (int k0 = 0; k0 < K; k0 += BK) {
    s16x8 ra0 = load8<AF32>(Ain, aOff + k0);
    s16x8 ra1 = load8<AF32>(Ain, aOff + k0 + aStep);
    s16x8 rb0 = load8<BF32>(Bin, bOff + k0);
    s16x8 rb1 = load8<BF32>(Bin, bOff + k0 + bStep);

    __syncthreads();  // prior iteration's LDS reads complete before overwrite
    *(s16x8*)(sA + sRow * BK + sCol)        = ra0;
    *(s16x8*)(sA + (sRow + 64) * BK + sCol) = ra1;
    *(s16x8*)(sB + sRow * BK + sCol)        = rb0;
    *(s16x8*)(sB + (sRow + 64) * BK + sCol) = rb1;
    __syncthreads();

    s16x8 af[4], bfr[4];
#pragma unroll
    for (int mi = 0; mi < 4; mi++)
      af[mi] = *(const s16x8*)(sA + (warpRow + mi * 16 + l16) * BK + quad * 8);
#pragma unroll
    for (int ni = 0; ni < 4; ni++)
      bfr[ni] = *(const s16x8*)(sB + (warpCol + ni * 16 + l16) * BK + quad * 8);
#pragma unroll
    for (int mi = 0; mi < 4; mi++)
#pragma unroll
      for (int ni = 0; ni < 4; ni++)
        acc[mi][ni] = __builtin_amdgcn_mfma_f32_16x16x32_bf16(af[mi], bfr[ni], acc[mi][ni], 0, 0, 0);
  }

  // epilogue: C/D layout col=lane&15, row=(lane>>4)*4+reg (verified m89/m91)
#pragma unroll
  for (int mi = 0; mi < 4; mi++) {
#pragma unroll
    for (int ni = 0; ni < 4; ni++) {
      f32x4 v = acc[mi][ni];
      const int col = tileN + warpCol + ni * 16 + l16;
#pragma unroll
      for (int r = 0; r < 4; r++) {
        const int row = tileM + warpRow + mi * 16 + quad * 4 + r;
        const float val = v[r] * alpha;
        size_t dst;
        if (MODE == 0) {
          // dest[(h*16+b)][s][e]: h=col>>9, b=row&15, s=row>>4, e=col&511
          dst = (((size_t)((col >> 9) * 16 + (row & 15)) * 512 + (size_t)(row >> 4)) * 512)
                + (size_t)(col & 511);
        } else {
          dst = cBase + (size_t)row * ldc + (size_t)col;
        }
        if (CF32) ((float*)Cout)[dst] = val;
        else      ((bf16*)Cout)[dst] = __float2bfloat16(val);
      }
    }
  }
}

// in-place fp32 softmax over 32768 contiguous rows of 512; one wave per row
__global__ __launch_bounds__(256) void softmax512f(float* __restrict__ P) {
  const int row  = blockIdx.x * 4 + (threadIdx.x >> 6);
  const int lane = threadIdx.x & 63;
  float* p = P + (size_t)row * 512 + lane * 8;

  f32x4 a = *(const f32x4*)p;
  f32x4 b = *(const f32x4*)(p + 4);
  float v[8];
  float m = -1e30f;
#pragma unroll
  for (int j = 0; j < 4; j++) { v[j] = a[j]; v[j + 4] = b[j]; }
#pragma unroll
  for (int j = 0; j < 8; j++) m = fmaxf(m, v[j]);
#pragma unroll
  for (int off = 32; off > 0; off >>= 1) m = fmaxf(m, __shfl_xor(m, off, 64));
  float s = 0.f;
#pragma unroll
  for (int j = 0; j < 8; j++) { v[j] = __expf(v[j] - m); s += v[j]; }
#pragma unroll
  for (int off = 32; off > 0; off >>= 1) s += __shfl_xor(s, off, 64);
  const float inv = 1.f / s;
  f32x4 oa, ob;
#pragma unroll
  for (int j = 0; j < 4; j++) { oa[j] = v[j] * inv; ob[j] = v[j + 4] * inv; }
  *(f32x4*)p = oa;
  *(f32x4*)(p + 4) = ob;
}

// batched 512x512 bf16 transpose: VT[n][e][t] = V[n][t][e]
__global__ __launch_bounds__(256) void transpose512(const bf16* __restrict__ V,
                                                    bf16* __restrict__ VT) {
  __shared__ bf16 tile[32][33];
  const int n = blockIdx.z;
  const bf16* src = V + (size_t)n * 262144;
  bf16* dst = VT + (size_t)n * 262144;
  const int x = blockIdx.x * 32 + threadIdx.x;
#pragma unroll
  for (int i = 0; i < 32; i += 8)
    tile[threadIdx.y + i][threadIdx.x] =
        src[(size_t)(blockIdx.y * 32 + threadIdx.y + i) * 512 + x];
  __syncthreads();
  const int tcol = blockIdx.y * 32 + threadIdx.x;
#pragma unroll
  for (int i = 0; i < 32; i += 8)
    dst[(size_t)(blockIdx.x * 32 + threadIdx.y + i) * 512 + tcol] =
        tile[threadIdx.x][threadIdx.y + i];
}

extern "C" void kernel_launch(void* const* d_in, const int* in_sizes, int n_in,
                              void* d_out, int out_size, void* d_ws, size_t ws_size,
                              hipStream_t stream) {
  const void* query = d_in[0];  // fp32 (512,16,2048)
  const void* key   = d_in[1];
  const void* value = d_in[2];
  const void* Wq = d_in[3];     // fp32 (2048,2048)
  const void* Wk = d_in[4];
  const void* Wv = d_in[5];
  const void* Wo = d_in[6];
  float* out = (float*)d_out;             // output (S,B,D) fp32, 16777216 elems
  float* P   = out + 16777216;            // attn_score (B,S,H,t) fp32, rows of 512

  // workspace (64 MB): bf16 Q,K projections; reused for VT and X
  bf16* Q  = (bf16*)d_ws;                 // ws[0:32MB)   -> later VT
  bf16* Kp = Q + 16777216;                // ws[32:64MB)  -> later X
  bf16* V  = (bf16*)d_out;                // park bf16 V in out[0:32MB); dead before final GEMM
  bf16* VT = Q;
  bf16* X  = Kp;

  const dim3 blk(256);
  const float inv_sqrt_hd = 0.04419417382415922f;  // 1/sqrt(512)

  // projections: (8192x2048) = in @ W^T, scatter to (H*B,S,hd) bf16
  gemm_nt<0, true, true, false><<<dim3(16, 64, 1), blk, 0, stream>>>(query, Wq, Q,  2048, 2048, 2048, 0, 1.0f);
  gemm_nt<0, true, true, false><<<dim3(16, 64, 1), blk, 0, stream>>>(key,   Wk, Kp, 2048, 2048, 2048, 0, 1.0f);
  gemm_nt<0, true, true, false><<<dim3(16, 64, 1), blk, 0, stream>>>(value, Wv, V,  2048, 2048, 2048, 0, 1.0f);
  // scores: per-head 512^3, fp32 epilogue straight into P region of d_out (final layout)
  gemm_nt<1, false, false, true><<<dim3(4, 4, 64), blk, 0, stream>>>(Q, Kp, P, 512, 512, 512, 2048, inv_sqrt_hd);
  // softmax in place on fp32 P
  softmax512f<<<dim3(8192), blk, 0, stream>>>(P);
  // V -> VT (bf16), VT overwrites dead Q
  transpose512<<<dim3(16, 16, 64), dim3(32, 8), 0, stream>>>(V, VT);
  // out_heads = P @ V as NT: A = fp32 P (converted in staging), B = bf16 VT; X bf16 (B,H,S,hd) flat
  gemm_nt<2, true, false, false><<<dim3(4, 4, 64), blk, 0, stream>>>(P, VT, X, 512, 2048, 512, 512, 1.0f);
  // final: out = X @ Wo^T, fp32 row-major (S,B,D); overwrites V parking region
  gemm_nt<3, false, true, true><<<dim3(16, 64, 1), blk, 0, stream>>>(X, Wo, out, 2048, 2048, 2048, 2048, 1.0f);
}